// Round 10
// baseline (373.464 us; speedup 1.0000x reference)
//
#include <hip/hip_runtime.h>
#include <hip/hip_bf16.h>
#include <math.h>

#define TM1 16
#define TT 17

typedef __attribute__((ext_vector_type(8))) __bf16 bf16x8;
typedef __attribute__((ext_vector_type(4))) float f32x4;

// ---------------- workspace layout (float units) ----------------
#define OFF_BSTATS 0          // 512*32 = 16384
#define OFF_SPB    16384      // 512*256 bf16 = 65536 f
#define OFF_PWB    81920      // 256*512 bf16 = 65536 f
#define OFF_WIHB   147456     // 1536*256 bf16 = 196608 f
#define OFF_WHHB   344064     // 1536*512 bf16 = 393216 f
#define OFF_HB     737280     // 2 x 512*512 bf16 = 262144 f
// total 999424 floats ~= 4.0 MB

// ---------------- Encoder pass A: conv (strip-blocked) + stats; + weight bf16 prep ----------------
// thread -> input row r = tid>>2, col strip cs = (tid&3)*16, processed as 2 chunks of 8 px.
// Per (chunk, c4, ci): rows rv[3][10] in regs -> each input px read once per c4 (480 LDS reads
// per thread vs 1152 scalar-gather) ; FMA unchanged (4608/thread).
__global__ __launch_bounds__(256) void enc_stats_prep(
    const float* __restrict__ x, const float* __restrict__ cw,
    float* __restrict__ bstats,
    const float* __restrict__ wih, const float* __restrict__ whh,
    const float* __restrict__ pw,
    __hip_bfloat16* __restrict__ wihb, __hip_bfloat16* __restrict__ whhb,
    __hip_bfloat16* __restrict__ pwb) {
  // grid-stride weight conversion (independent of conv work)
  {
    const int n1 = 1536 * 256, n2 = 1536 * 512, n3 = 256 * 512;
    int i = blockIdx.x * 256 + threadIdx.x;
    int st = gridDim.x * 256;
    for (int j = i; j < n1 + n2 + n3; j += st) {
      if (j < n1) {
        int r = j >> 8, c = j & 255;
        wihb[j] = __float2bfloat16(wih[r * 258 + c]);
      } else if (j < n1 + n2) {
        int k = j - n1;
        whhb[k] = __float2bfloat16(whh[k]);
      } else {
        int k = j - n1 - n2;
        pwb[k] = __float2bfloat16(pw[k]);
      }
    }
  }

  __shared__ float imgp[2 * 66 * 66];
  __shared__ float reds[4][16], redq[4][16];
  const int b = blockIdx.x, tid = threadIdx.x;
  const int wv = tid >> 6;
  for (int i = tid; i < 2 * 66 * 66; i += 256) imgp[i] = 0.0f;
  __syncthreads();
  const float* xb = x + b * 8192;
  for (int i = tid; i < 8192; i += 256) {
    int ci = i >> 12, rem = i & 4095, y = rem >> 6, xx = rem & 63;
    imgp[ci * 4356 + (y + 1) * 66 + (xx + 1)] = xb[i];
  }
  __syncthreads();

  const int r = tid >> 2;
  const int cs = (tid & 3) << 4;

  float s[16], q[16];
#pragma unroll
  for (int c = 0; c < 16; ++c) { s[c] = 0.0f; q[c] = 0.0f; }

#pragma unroll
  for (int half = 0; half < 2; ++half) {
    const int c0 = cs + half * 8;
#pragma unroll
    for (int c4 = 0; c4 < 4; ++c4) {
      float a[4][8];
#pragma unroll
      for (int ch = 0; ch < 4; ++ch)
#pragma unroll
        for (int j = 0; j < 8; ++j) a[ch][j] = 0.0f;
#pragma unroll
      for (int ci = 0; ci < 2; ++ci) {
        float wk[4][9];
#pragma unroll
        for (int ch = 0; ch < 4; ++ch)
#pragma unroll
          for (int k = 0; k < 9; ++k)
            wk[ch][k] = cw[(c4 * 4 + ch) * 18 + ci * 9 + k];
        float rv[3][10];
#pragma unroll
        for (int dy = 0; dy < 3; ++dy)
#pragma unroll
          for (int j = 0; j < 10; ++j)
            rv[dy][j] = imgp[ci * 4356 + (r + dy) * 66 + c0 + j];
#pragma unroll
        for (int j = 0; j < 8; ++j)
#pragma unroll
          for (int ch = 0; ch < 4; ++ch) {
            float acc = a[ch][j];
#pragma unroll
            for (int dy = 0; dy < 3; ++dy) {
              acc = fmaf(wk[ch][dy * 3 + 0], rv[dy][j + 0], acc);
              acc = fmaf(wk[ch][dy * 3 + 1], rv[dy][j + 1], acc);
              acc = fmaf(wk[ch][dy * 3 + 2], rv[dy][j + 2], acc);
            }
            a[ch][j] = acc;
          }
      }
#pragma unroll
      for (int ch = 0; ch < 4; ++ch)
#pragma unroll
        for (int j = 0; j < 8; ++j) {
          const float v = a[ch][j];
          s[c4 * 4 + ch] += v;
          q[c4 * 4 + ch] = fmaf(v, v, q[c4 * 4 + ch]);
        }
    }
  }

  // wave reduce 16 sums + 16 sumsqs
#pragma unroll
  for (int c = 0; c < 16; ++c) {
    float sv = s[c], qv = q[c];
#pragma unroll
    for (int off = 32; off >= 1; off >>= 1) {
      sv += __shfl_down(sv, off);
      qv += __shfl_down(qv, off);
    }
    if ((tid & 63) == 0) { reds[wv][c] = sv; redq[wv][c] = qv; }
  }
  __syncthreads();
  if (tid < 16)
    bstats[b * 32 + tid] = reds[0][tid] + reds[1][tid] + reds[2][tid] + reds[3][tid];
  else if (tid < 32) {
    int c = tid - 16;
    bstats[b * 32 + tid] = redq[0][c] + redq[1][c] + redq[2][c] + redq[3][c];
  }
}

// ---- Encoder pass B: stats reduce + conv (strip-blocked) + BN + relu + maxpool + avg + FC ----
// thread -> out row py = tid>>3, out cols [ocs, ocs+4) as 2 pairs. Per (c4, pair, ci):
// rows rv[4][6] in regs -> 384 LDS reads/thread (was ~4600 scalar-gather).
__global__ __launch_bounds__(256) void enc_finish(const float* __restrict__ x,
                                                  const float* __restrict__ cw,
                                                  const float* __restrict__ bstats,
                                                  const float* __restrict__ gamma,
                                                  const float* __restrict__ beta,
                                                  const float* __restrict__ fcw,
                                                  const float* __restrict__ fcb,
                                                  __hip_bfloat16* __restrict__ spb,
                                                  float* __restrict__ out) {
  __shared__ float imgp[2 * 66 * 66];
  __shared__ float red[4][16];
  __shared__ float plds[16];
  __shared__ float statsL[32];
  __shared__ float racc[8][32];
  const int b = blockIdx.x, tid = threadIdx.x;
  const int wv = tid >> 6;

  {
    const int c = tid & 31, part = tid >> 5;
    float s = 0;
    for (int bb = part; bb < 512; bb += 8) s += bstats[bb * 32 + c];
    racc[part][c] = s;
  }
  for (int i = tid; i < 2 * 66 * 66; i += 256) imgp[i] = 0.0f;
  __syncthreads();
  if (tid < 32) {
    float v = 0;
#pragma unroll
    for (int p = 0; p < 8; ++p) v += racc[p][tid];
    statsL[tid] = v;
  }
  const float* xb = x + b * 8192;
  for (int i = tid; i < 8192; i += 256) {
    int ci = i >> 12, rem = i & 4095, y = rem >> 6, xx = rem & 63;
    imgp[ci * 4356 + (y + 1) * 66 + (xx + 1)] = xb[i];
  }
  __syncthreads();

  const float invN = 1.0f / (512.0f * 4096.0f);
  const int py = tid >> 3;
  const int ocs = (tid & 7) << 2;

  float psum[16];
#pragma unroll
  for (int c = 0; c < 16; ++c) psum[c] = 0.0f;

#pragma unroll
  for (int c4 = 0; c4 < 4; ++c4) {
    float sc[4], sh[4];
#pragma unroll
    for (int ch = 0; ch < 4; ++ch) {
      const int c = c4 * 4 + ch;
      const float m = statsL[c] * invN;
      const float var = statsL[16 + c] * invN - m * m;
      const float isd = rsqrtf(var + 1e-5f);
      sc[ch] = gamma[c] * isd;
      sh[ch] = beta[c] - m * sc[ch];
    }
#pragma unroll
    for (int op = 0; op < 2; ++op) {
      const int oc = ocs + op * 2;   // 2 output px
      const int ic = oc * 2;         // input col base; cols ic..ic+5
      float a[4][8];
#pragma unroll
      for (int ch = 0; ch < 4; ++ch)
#pragma unroll
        for (int j = 0; j < 8; ++j) a[ch][j] = 0.0f;
#pragma unroll
      for (int ci = 0; ci < 2; ++ci) {
        float wk[4][9];
#pragma unroll
        for (int ch = 0; ch < 4; ++ch)
#pragma unroll
          for (int k = 0; k < 9; ++k)
            wk[ch][k] = cw[(c4 * 4 + ch) * 18 + ci * 9 + k];
        float rv[4][6];
#pragma unroll
        for (int dy = 0; dy < 4; ++dy)
#pragma unroll
          for (int j = 0; j < 6; ++j)
            rv[dy][j] = imgp[ci * 4356 + (2 * py + dy) * 66 + ic + j];
#pragma unroll
        for (int ry = 0; ry < 2; ++ry)
#pragma unroll
          for (int rx = 0; rx < 4; ++rx)
#pragma unroll
            for (int ch = 0; ch < 4; ++ch) {
              float acc = a[ch][ry * 4 + rx];
#pragma unroll
              for (int dy = 0; dy < 3; ++dy) {
                acc = fmaf(wk[ch][dy * 3 + 0], rv[ry + dy][rx + 0], acc);
                acc = fmaf(wk[ch][dy * 3 + 1], rv[ry + dy][rx + 1], acc);
                acc = fmaf(wk[ch][dy * 3 + 2], rv[ry + dy][rx + 2], acc);
              }
              a[ch][ry * 4 + rx] = acc;
            }
      }
      // BN + relu + 2x2 maxpool for the 2 output px
#pragma unroll
      for (int ch = 0; ch < 4; ++ch)
#pragma unroll
        for (int j = 0; j < 2; ++j) {
          const float v00 = fmaxf(fmaf(a[ch][2 * j + 0], sc[ch], sh[ch]), 0.0f);
          const float v01 = fmaxf(fmaf(a[ch][2 * j + 1], sc[ch], sh[ch]), 0.0f);
          const float v10 = fmaxf(fmaf(a[ch][4 + 2 * j + 0], sc[ch], sh[ch]), 0.0f);
          const float v11 = fmaxf(fmaf(a[ch][4 + 2 * j + 1], sc[ch], sh[ch]), 0.0f);
          psum[c4 * 4 + ch] += fmaxf(fmaxf(v00, v01), fmaxf(v10, v11));
        }
    }
  }

  // block-reduce psum[16] -> plds
#pragma unroll
  for (int c = 0; c < 16; ++c) {
    float v = psum[c];
#pragma unroll
    for (int off = 32; off >= 1; off >>= 1) v += __shfl_down(v, off);
    if ((tid & 63) == 0) red[wv][c] = v;
  }
  __syncthreads();
  if (tid < 16)
    plds[tid] = (red[0][tid] + red[1][tid] + red[2][tid] + red[3][tid]) * (1.0f / 1024.0f);
  __syncthreads();

  float acc = fcb[tid];
#pragma unroll
  for (int c = 0; c < 16; ++c) acc = fmaf(plds[c], fcw[tid * 16 + c], acc);
  spb[b * 256 + tid] = __float2bfloat16(acc);
  out[(b * TT + 0) * 256 + tid] = acc;
}

// ---------------- GRU gates, gate-per-wave: 512 blocks x 384 thr (6 waves) ----------------
__global__ __launch_bounds__(384) void gru_v2(
    const __hip_bfloat16* __restrict__ spb,
    const __hip_bfloat16* __restrict__ hb_in,
    __hip_bfloat16* __restrict__ hb_out,
    const __hip_bfloat16* __restrict__ wihb,   // [1536][256]
    const __hip_bfloat16* __restrict__ whhb,   // [1536][512]
    const float* __restrict__ wih,             // fp32, u-tail cols 256,257
    const float* __restrict__ actions,         // [512][16][2]
    const float* __restrict__ bih, const float* __restrict__ bhh,
    int t) {
  __shared__ __hip_bfloat16 sF[8 * 64 * 8];    // 8KB:  s A-frags, frag-order
  __shared__ __hip_bfloat16 hF[16 * 64 * 8];   // 16KB: h A-frags, frag-order
  __shared__ float accL[4][2][256];            // 8KB
  const int tid = threadIdx.x;
  const int w = tid / 64, lane = tid & 63;
  const int l15 = lane & 15, hi = lane >> 4;
  const int cg = blockIdx.x, band = blockIdx.y;
  const int row0 = band * 16;
  const int ct = w & 1, g = w >> 1;

  for (int i = tid; i < 512; i += 384) {
    int kk = i >> 6, ln = i & 63;
    *(bf16x8*)(sF + i * 8) =
        *(const bf16x8*)(spb + (row0 + (ln & 15)) * 256 + kk * 32 + (ln >> 4) * 8);
  }
  if (t > 0) {
    for (int i = tid; i < 1024; i += 384) {
      int kk = i >> 6, ln = i & 63;
      *(bf16x8*)(hF + i * 8) =
          *(const bf16x8*)(hb_in + (row0 + (ln & 15)) * 512 + kk * 32 + (ln >> 4) * 8);
    }
  }
  __syncthreads();

  const int cj = cg * 32 + ct * 16;
  f32x4 accS = {0.f, 0.f, 0.f, 0.f}, accH = accS;
  {
    const __hip_bfloat16* B = wihb + (g * 512 + cj + l15) * 256 + hi * 8;
#pragma unroll
    for (int kk = 0; kk < 8; ++kk) {
      bf16x8 a = *(const bf16x8*)(sF + (kk * 64 + lane) * 8);
      accS = __builtin_amdgcn_mfma_f32_16x16x32_bf16(a, *(const bf16x8*)(B + kk * 32),
                                                     accS, 0, 0, 0);
    }
  }
  if (t > 0) {
    const __hip_bfloat16* B = whhb + (g * 512 + cj + l15) * 512 + hi * 8;
#pragma unroll
    for (int kk = 0; kk < 16; ++kk) {
      bf16x8 a = *(const bf16x8*)(hF + (kk * 64 + lane) * 8);
      accH = __builtin_amdgcn_mfma_f32_16x16x32_bf16(a, *(const bf16x8*)(B + kk * 32),
                                                     accH, 0, 0, 0);
    }
  }
  if (g < 2) {
#pragma unroll
    for (int i = 0; i < 4; ++i)
      accL[g][ct][(hi * 4 + i) * 16 + l15] = accS[i] + accH[i];
  } else {
#pragma unroll
    for (int i = 0; i < 4; ++i) {
      accL[2][ct][(hi * 4 + i) * 16 + l15] = accS[i];
      accL[3][ct][(hi * 4 + i) * 16 + l15] = accH[i];
    }
  }
  __syncthreads();

  if (w < 2) {
    f32x4 vR = *(const f32x4*)&accL[0][w][lane * 4];
    f32x4 vZ = *(const f32x4*)&accL[1][w][lane * 4];
    f32x4 vXN = *(const f32x4*)&accL[2][w][lane * 4];
    f32x4 vHN = *(const f32x4*)&accL[3][w][lane * 4];
    const int r = lane >> 2;
    const int row = row0 + r;
    const float u0 = actions[row * 32 + t * 2 + 0];
    const float u1 = actions[row * 32 + t * 2 + 1];
#pragma unroll
    for (int j = 0; j < 4; ++j) {
      const int c = (lane & 3) * 4 + j;
      const int col = cg * 32 + w * 16 + c;
      const float br = bih[col] + bhh[col];
      const float bz = bih[512 + col] + bhh[512 + col];
      const float bxn = bih[1024 + col];
      const float bhn = bhh[1024 + col];
      const float wur = wih[col * 258 + 256], wvr = wih[col * 258 + 257];
      const float wuz = wih[(512 + col) * 258 + 256], wvz = wih[(512 + col) * 258 + 257];
      const float wun = wih[(1024 + col) * 258 + 256], wvn = wih[(1024 + col) * 258 + 257];
      const float gr = vR[j] + br + u0 * wur + u1 * wvr;
      const float gz = vZ[j] + bz + u0 * wuz + u1 * wvz;
      const float gxn = vXN[j] + bxn + u0 * wun + u1 * wvn;
      const float ghn = vHN[j] + bhn;
      const float rg = 1.0f / (1.0f + __expf(-gr));
      const float zg = 1.0f / (1.0f + __expf(-gz));
      float xn = gxn + rg * ghn;
      xn = fminf(fmaxf(xn, -15.0f), 15.0f);
      const float e = __expf(2.0f * xn);
      const float ng = (e - 1.0f) / (e + 1.0f);
      const float hp = (t > 0) ? (float)hb_in[row * 512 + col] : 0.0f;
      const float hnv = (1.0f - zg) * ng + zg * hp;
      hb_out[row * 512 + col] = __float2bfloat16(hnv);
    }
  }
}

// ---------------- pred, split-K-4: 512 blocks x 256 thr (4 waves) ----------------
__global__ __launch_bounds__(256) void pred_v2(
    const __hip_bfloat16* __restrict__ hb,
    const __hip_bfloat16* __restrict__ pwb,    // [256][512]
    const float* __restrict__ pb,
    float* __restrict__ out,
    __hip_bfloat16* __restrict__ spb,
    int slot) {
  __shared__ float accL[4][256];
  const int tid = threadIdx.x;
  const int w = tid >> 6, lane = tid & 63;
  const int l15 = lane & 15, hi = lane >> 4;
  const int pcg = blockIdx.x, band = blockIdx.y;
  const int row0 = band * 16, pc0 = pcg * 16;
  f32x4 acc = {0.f, 0.f, 0.f, 0.f};
  const __hip_bfloat16* A = hb + (row0 + l15) * 512 + w * 128 + hi * 8;
  const __hip_bfloat16* B = pwb + (pc0 + l15) * 512 + w * 128 + hi * 8;
#pragma unroll
  for (int kk = 0; kk < 4; ++kk)
    acc = __builtin_amdgcn_mfma_f32_16x16x32_bf16(*(const bf16x8*)(A + kk * 32),
                                                  *(const bf16x8*)(B + kk * 32),
                                                  acc, 0, 0, 0);
#pragma unroll
  for (int i = 0; i < 4; ++i) accL[w][(hi * 4 + i) * 16 + l15] = acc[i];
  __syncthreads();
  if (w == 0) {
    f32x4 p0 = *(const f32x4*)&accL[0][lane * 4];
    f32x4 p1 = *(const f32x4*)&accL[1][lane * 4];
    f32x4 p2 = *(const f32x4*)&accL[2][lane * 4];
    f32x4 p3 = *(const f32x4*)&accL[3][lane * 4];
    const int r = lane >> 2;
    const int row = row0 + r;
    float4 ov;
    float* po = &ov.x;
#pragma unroll
    for (int j = 0; j < 4; ++j) {
      const int c = (lane & 3) * 4 + j;
      const int col = pc0 + c;
      float v = p0[j] + p1[j] + p2[j] + p3[j] + pb[col];
      v = fmaxf(v, 0.0f);
      po[j] = v;
      spb[row * 256 + col] = __float2bfloat16(v);
    }
    *(float4*)(out + ((size_t)row * TT + slot) * 256 + pc0 + (lane & 3) * 4) = ov;
  }
}

extern "C" void kernel_launch(void* const* d_in, const int* in_sizes, int n_in,
                              void* d_out, int out_size, void* d_ws, size_t ws_size,
                              hipStream_t stream) {
  const float* x       = (const float*)d_in[0];
  const float* actions = (const float*)d_in[1];
  const float* cw      = (const float*)d_in[2];
  const float* gamma   = (const float*)d_in[3];
  const float* beta    = (const float*)d_in[4];
  const float* fcw     = (const float*)d_in[5];
  const float* fcb     = (const float*)d_in[6];
  const float* wih     = (const float*)d_in[7];
  const float* whh     = (const float*)d_in[8];
  const float* bih     = (const float*)d_in[9];
  const float* bhh     = (const float*)d_in[10];
  const float* pw      = (const float*)d_in[11];
  const float* pb      = (const float*)d_in[12];
  float* out = (float*)d_out;
  float* ws  = (float*)d_ws;

  float* bstats = ws + OFF_BSTATS;
  __hip_bfloat16* spb  = (__hip_bfloat16*)(ws + OFF_SPB);
  __hip_bfloat16* pwb  = (__hip_bfloat16*)(ws + OFF_PWB);
  __hip_bfloat16* wihb = (__hip_bfloat16*)(ws + OFF_WIHB);
  __hip_bfloat16* whhb = (__hip_bfloat16*)(ws + OFF_WHHB);
  __hip_bfloat16* hb0  = (__hip_bfloat16*)(ws + OFF_HB);
  __hip_bfloat16* hb1  = hb0 + 512 * 512;

  enc_stats_prep<<<dim3(512), dim3(256), 0, stream>>>(x, cw, bstats, wih, whh, pw,
                                                      wihb, whhb, pwb);
  enc_finish<<<dim3(512), dim3(256), 0, stream>>>(x, cw, bstats, gamma, beta, fcw, fcb,
                                                  spb, out);
  for (int t = 0; t < TM1; ++t) {
    __hip_bfloat16* hbi = (t & 1) ? hb1 : hb0;
    __hip_bfloat16* hbo = (t & 1) ? hb0 : hb1;
    gru_v2<<<dim3(16, 32), dim3(384), 0, stream>>>(spb, hbi, hbo, wihb, whhb,
                                                   wih, actions, bih, bhh, t);
    pred_v2<<<dim3(16, 32), dim3(256), 0, stream>>>(hbo, pwb, pb, out, spb, t + 1);
  }
}

// Round 11
// 364.052 us; speedup vs baseline: 1.0259x; 1.0259x over previous
//
#include <hip/hip_runtime.h>
#include <hip/hip_bf16.h>
#include <math.h>

#define TM1 16
#define TT 17

typedef __attribute__((ext_vector_type(8))) __bf16 bf16x8;
typedef __attribute__((ext_vector_type(4))) float f32x4;

// ---------------- workspace layout (float units) ----------------
#define OFF_BSTATS 0          // 512*32 = 16384
#define OFF_SPB    16384      // 512*256 bf16 = 65536 f
#define OFF_PWB    81920      // 256*512 bf16 = 65536 f
#define OFF_WIHB   147456     // 1536*256 bf16 = 196608 f
#define OFF_WHHB   344064     // 1536*512 bf16 = 393216 f
#define OFF_HB     737280     // 2 x 512*512 bf16 = 262144 f
// total 999424 floats ~= 4.0 MB

#define IMG_STRIDE 67
#define IMG_CI (66 * IMG_STRIDE)   // 4422

// ---------------- Encoder pass A: conv (pass-B-style blocking) + stats; + weight prep ----------------
// thread -> conv rows {2py, 2py+1}, cols [8*(tid&7), +8) in 2 chunks of 4.
// rv[2][4][6] hoisted per chunk: 96 vector LDS reads/thread total.
// #pragma unroll 1 on chunk loop keeps VGPR bounded; c4 unrolled so s[]/q[] stay static.
__global__ __launch_bounds__(256) void enc_stats_prep(
    const float* __restrict__ x, const float* __restrict__ cw,
    float* __restrict__ bstats,
    const float* __restrict__ wih, const float* __restrict__ whh,
    const float* __restrict__ pw,
    __hip_bfloat16* __restrict__ wihb, __hip_bfloat16* __restrict__ whhb,
    __hip_bfloat16* __restrict__ pwb) {
  // grid-stride weight conversion (independent of conv work)
  {
    const int n1 = 1536 * 256, n2 = 1536 * 512, n3 = 256 * 512;
    int i = blockIdx.x * 256 + threadIdx.x;
    int st = gridDim.x * 256;
    for (int j = i; j < n1 + n2 + n3; j += st) {
      if (j < n1) {
        int r = j >> 8, c = j & 255;
        wihb[j] = __float2bfloat16(wih[r * 258 + c]);
      } else if (j < n1 + n2) {
        int k = j - n1;
        whhb[k] = __float2bfloat16(whh[k]);
      } else {
        int k = j - n1 - n2;
        pwb[k] = __float2bfloat16(pw[k]);
      }
    }
  }

  __shared__ float imgp[2 * IMG_CI];
  __shared__ float reds[4][16], redq[4][16];
  const int b = blockIdx.x, tid = threadIdx.x;
  const int wv = tid >> 6;
  for (int i = tid; i < 2 * IMG_CI; i += 256) imgp[i] = 0.0f;
  __syncthreads();
  const float* xb = x + b * 8192;
  for (int i = tid; i < 8192; i += 256) {
    int ci = i >> 12, rem = i & 4095, y = rem >> 6, xx = rem & 63;
    imgp[ci * IMG_CI + (y + 1) * IMG_STRIDE + (xx + 1)] = xb[i];
  }
  __syncthreads();

  const int py = tid >> 3;        // 0..31 -> conv rows 2py, 2py+1
  const int cb = (tid & 7) << 3;  // col base (8 cols, 2 chunks of 4)

  float s[16], q[16];
#pragma unroll
  for (int c = 0; c < 16; ++c) { s[c] = 0.0f; q[c] = 0.0f; }

#pragma unroll 1
  for (int op = 0; op < 2; ++op) {
    const int ic = cb + 4 * op;  // conv cols ic..ic+3; padded input cols ic..ic+5
    float rv[2][4][6];
#pragma unroll
    for (int ci = 0; ci < 2; ++ci)
#pragma unroll
      for (int dy = 0; dy < 4; ++dy)
#pragma unroll
        for (int j = 0; j < 6; ++j)
          rv[ci][dy][j] = imgp[ci * IMG_CI + (2 * py + dy) * IMG_STRIDE + ic + j];
#pragma unroll
    for (int c4 = 0; c4 < 4; ++c4) {
      float a[4][8];
#pragma unroll
      for (int ch = 0; ch < 4; ++ch)
#pragma unroll
        for (int j = 0; j < 8; ++j) a[ch][j] = 0.0f;
#pragma unroll
      for (int ci = 0; ci < 2; ++ci) {
        float wk[4][9];
#pragma unroll
        for (int ch = 0; ch < 4; ++ch)
#pragma unroll
          for (int k = 0; k < 9; ++k)
            wk[ch][k] = cw[(c4 * 4 + ch) * 18 + ci * 9 + k];
#pragma unroll
        for (int ry = 0; ry < 2; ++ry)
#pragma unroll
          for (int rx = 0; rx < 4; ++rx)
#pragma unroll
            for (int ch = 0; ch < 4; ++ch) {
              float acc = a[ch][ry * 4 + rx];
#pragma unroll
              for (int dy = 0; dy < 3; ++dy) {
                acc = fmaf(wk[ch][dy * 3 + 0], rv[ci][ry + dy][rx + 0], acc);
                acc = fmaf(wk[ch][dy * 3 + 1], rv[ci][ry + dy][rx + 1], acc);
                acc = fmaf(wk[ch][dy * 3 + 2], rv[ci][ry + dy][rx + 2], acc);
              }
              a[ch][ry * 4 + rx] = acc;
            }
      }
#pragma unroll
      for (int ch = 0; ch < 4; ++ch)
#pragma unroll
        for (int j = 0; j < 8; ++j) {
          const float v = a[ch][j];
          s[c4 * 4 + ch] += v;
          q[c4 * 4 + ch] = fmaf(v, v, q[c4 * 4 + ch]);
        }
    }
  }

  // wave reduce 16 sums + 16 sumsqs
#pragma unroll
  for (int c = 0; c < 16; ++c) {
    float sv = s[c], qv = q[c];
#pragma unroll
    for (int off = 32; off >= 1; off >>= 1) {
      sv += __shfl_down(sv, off);
      qv += __shfl_down(qv, off);
    }
    if ((tid & 63) == 0) { reds[wv][c] = sv; redq[wv][c] = qv; }
  }
  __syncthreads();
  if (tid < 16)
    bstats[b * 32 + tid] = reds[0][tid] + reds[1][tid] + reds[2][tid] + reds[3][tid];
  else if (tid < 32) {
    int c = tid - 16;
    bstats[b * 32 + tid] = redq[0][c] + redq[1][c] + redq[2][c] + redq[3][c];
  }
}

// ---- Encoder pass B: stats reduce + conv + BN + relu + maxpool + avg + FC ----
// Same blocking as pass A; fold = BN+relu+2x2 maxpool into psum.
__global__ __launch_bounds__(256) void enc_finish(const float* __restrict__ x,
                                                  const float* __restrict__ cw,
                                                  const float* __restrict__ bstats,
                                                  const float* __restrict__ gamma,
                                                  const float* __restrict__ beta,
                                                  const float* __restrict__ fcw,
                                                  const float* __restrict__ fcb,
                                                  __hip_bfloat16* __restrict__ spb,
                                                  float* __restrict__ out) {
  __shared__ float imgp[2 * IMG_CI];
  __shared__ float red[4][16];
  __shared__ float plds[16];
  __shared__ float statsL[32];
  __shared__ float racc[8][32];
  const int b = blockIdx.x, tid = threadIdx.x;
  const int wv = tid >> 6;

  {
    const int c = tid & 31, part = tid >> 5;
    float s = 0;
    for (int bb = part; bb < 512; bb += 8) s += bstats[bb * 32 + c];
    racc[part][c] = s;
  }
  for (int i = tid; i < 2 * IMG_CI; i += 256) imgp[i] = 0.0f;
  __syncthreads();
  if (tid < 32) {
    float v = 0;
#pragma unroll
    for (int p = 0; p < 8; ++p) v += racc[p][tid];
    statsL[tid] = v;
  }
  const float* xb = x + b * 8192;
  for (int i = tid; i < 8192; i += 256) {
    int ci = i >> 12, rem = i & 4095, y = rem >> 6, xx = rem & 63;
    imgp[ci * IMG_CI + (y + 1) * IMG_STRIDE + (xx + 1)] = xb[i];
  }
  __syncthreads();

  const float invN = 1.0f / (512.0f * 4096.0f);
  const int py = tid >> 3;        // pool row 0..31
  const int cb = (tid & 7) << 3;

  float psum[16];
#pragma unroll
  for (int c = 0; c < 16; ++c) psum[c] = 0.0f;

#pragma unroll 1
  for (int op = 0; op < 2; ++op) {
    const int ic = cb + 4 * op;  // conv cols ic..ic+3 -> pool outputs ic/2, ic/2+1
    float rv[2][4][6];
#pragma unroll
    for (int ci = 0; ci < 2; ++ci)
#pragma unroll
      for (int dy = 0; dy < 4; ++dy)
#pragma unroll
        for (int j = 0; j < 6; ++j)
          rv[ci][dy][j] = imgp[ci * IMG_CI + (2 * py + dy) * IMG_STRIDE + ic + j];
#pragma unroll
    for (int c4 = 0; c4 < 4; ++c4) {
      float a[4][8];
#pragma unroll
      for (int ch = 0; ch < 4; ++ch)
#pragma unroll
        for (int j = 0; j < 8; ++j) a[ch][j] = 0.0f;
#pragma unroll
      for (int ci = 0; ci < 2; ++ci) {
        float wk[4][9];
#pragma unroll
        for (int ch = 0; ch < 4; ++ch)
#pragma unroll
          for (int k = 0; k < 9; ++k)
            wk[ch][k] = cw[(c4 * 4 + ch) * 18 + ci * 9 + k];
#pragma unroll
        for (int ry = 0; ry < 2; ++ry)
#pragma unroll
          for (int rx = 0; rx < 4; ++rx)
#pragma unroll
            for (int ch = 0; ch < 4; ++ch) {
              float acc = a[ch][ry * 4 + rx];
#pragma unroll
              for (int dy = 0; dy < 3; ++dy) {
                acc = fmaf(wk[ch][dy * 3 + 0], rv[ci][ry + dy][rx + 0], acc);
                acc = fmaf(wk[ch][dy * 3 + 1], rv[ci][ry + dy][rx + 1], acc);
                acc = fmaf(wk[ch][dy * 3 + 2], rv[ci][ry + dy][rx + 2], acc);
              }
              a[ch][ry * 4 + rx] = acc;
            }
      }
#pragma unroll
      for (int ch = 0; ch < 4; ++ch) {
        const int c = c4 * 4 + ch;
        const float m = statsL[c] * invN;
        const float var = statsL[16 + c] * invN - m * m;
        const float isd = rsqrtf(var + 1e-5f);
        const float sc = gamma[c] * isd;
        const float sh = beta[c] - m * sc;
#pragma unroll
        for (int j = 0; j < 2; ++j) {
          const float v00 = fmaxf(fmaf(a[ch][2 * j + 0], sc, sh), 0.0f);
          const float v01 = fmaxf(fmaf(a[ch][2 * j + 1], sc, sh), 0.0f);
          const float v10 = fmaxf(fmaf(a[ch][4 + 2 * j + 0], sc, sh), 0.0f);
          const float v11 = fmaxf(fmaf(a[ch][4 + 2 * j + 1], sc, sh), 0.0f);
          psum[c] += fmaxf(fmaxf(v00, v01), fmaxf(v10, v11));
        }
      }
    }
  }

#pragma unroll
  for (int c = 0; c < 16; ++c) {
    float v = psum[c];
#pragma unroll
    for (int off = 32; off >= 1; off >>= 1) v += __shfl_down(v, off);
    if ((tid & 63) == 0) red[wv][c] = v;
  }
  __syncthreads();
  if (tid < 16)
    plds[tid] = (red[0][tid] + red[1][tid] + red[2][tid] + red[3][tid]) * (1.0f / 1024.0f);
  __syncthreads();

  float acc = fcb[tid];
#pragma unroll
  for (int c = 0; c < 16; ++c) acc = fmaf(plds[c], fcw[tid * 16 + c], acc);
  spb[b * 256 + tid] = __float2bfloat16(acc);
  out[(b * TT + 0) * 256 + tid] = acc;
}

// ---------------- GRU gates, gate-per-wave: 512 blocks x 384 thr (6 waves) ----------------
__global__ __launch_bounds__(384) void gru_v2(
    const __hip_bfloat16* __restrict__ spb,
    const __hip_bfloat16* __restrict__ hb_in,
    __hip_bfloat16* __restrict__ hb_out,
    const __hip_bfloat16* __restrict__ wihb,   // [1536][256]
    const __hip_bfloat16* __restrict__ whhb,   // [1536][512]
    const float* __restrict__ wih,             // fp32, u-tail cols 256,257
    const float* __restrict__ actions,         // [512][16][2]
    const float* __restrict__ bih, const float* __restrict__ bhh,
    int t) {
  __shared__ __hip_bfloat16 sF[8 * 64 * 8];    // 8KB:  s A-frags, frag-order
  __shared__ __hip_bfloat16 hF[16 * 64 * 8];   // 16KB: h A-frags, frag-order
  __shared__ float accL[4][2][256];            // 8KB
  const int tid = threadIdx.x;
  const int w = tid / 64, lane = tid & 63;
  const int l15 = lane & 15, hi = lane >> 4;
  const int cg = blockIdx.x, band = blockIdx.y;
  const int row0 = band * 16;
  const int ct = w & 1, g = w >> 1;

  for (int i = tid; i < 512; i += 384) {
    int kk = i >> 6, ln = i & 63;
    *(bf16x8*)(sF + i * 8) =
        *(const bf16x8*)(spb + (row0 + (ln & 15)) * 256 + kk * 32 + (ln >> 4) * 8);
  }
  if (t > 0) {
    for (int i = tid; i < 1024; i += 384) {
      int kk = i >> 6, ln = i & 63;
      *(bf16x8*)(hF + i * 8) =
          *(const bf16x8*)(hb_in + (row0 + (ln & 15)) * 512 + kk * 32 + (ln >> 4) * 8);
    }
  }
  __syncthreads();

  const int cj = cg * 32 + ct * 16;
  f32x4 accS = {0.f, 0.f, 0.f, 0.f}, accH = accS;
  {
    const __hip_bfloat16* B = wihb + (g * 512 + cj + l15) * 256 + hi * 8;
#pragma unroll
    for (int kk = 0; kk < 8; ++kk) {
      bf16x8 a = *(const bf16x8*)(sF + (kk * 64 + lane) * 8);
      accS = __builtin_amdgcn_mfma_f32_16x16x32_bf16(a, *(const bf16x8*)(B + kk * 32),
                                                     accS, 0, 0, 0);
    }
  }
  if (t > 0) {
    const __hip_bfloat16* B = whhb + (g * 512 + cj + l15) * 512 + hi * 8;
#pragma unroll
    for (int kk = 0; kk < 16; ++kk) {
      bf16x8 a = *(const bf16x8*)(hF + (kk * 64 + lane) * 8);
      accH = __builtin_amdgcn_mfma_f32_16x16x32_bf16(a, *(const bf16x8*)(B + kk * 32),
                                                     accH, 0, 0, 0);
    }
  }
  if (g < 2) {
#pragma unroll
    for (int i = 0; i < 4; ++i)
      accL[g][ct][(hi * 4 + i) * 16 + l15] = accS[i] + accH[i];
  } else {
#pragma unroll
    for (int i = 0; i < 4; ++i) {
      accL[2][ct][(hi * 4 + i) * 16 + l15] = accS[i];
      accL[3][ct][(hi * 4 + i) * 16 + l15] = accH[i];
    }
  }
  __syncthreads();

  if (w < 2) {
    f32x4 vR = *(const f32x4*)&accL[0][w][lane * 4];
    f32x4 vZ = *(const f32x4*)&accL[1][w][lane * 4];
    f32x4 vXN = *(const f32x4*)&accL[2][w][lane * 4];
    f32x4 vHN = *(const f32x4*)&accL[3][w][lane * 4];
    const int r = lane >> 2;
    const int row = row0 + r;
    const float u0 = actions[row * 32 + t * 2 + 0];
    const float u1 = actions[row * 32 + t * 2 + 1];
#pragma unroll
    for (int j = 0; j < 4; ++j) {
      const int c = (lane & 3) * 4 + j;
      const int col = cg * 32 + w * 16 + c;
      const float br = bih[col] + bhh[col];
      const float bz = bih[512 + col] + bhh[512 + col];
      const float bxn = bih[1024 + col];
      const float bhn = bhh[1024 + col];
      const float wur = wih[col * 258 + 256], wvr = wih[col * 258 + 257];
      const float wuz = wih[(512 + col) * 258 + 256], wvz = wih[(512 + col) * 258 + 257];
      const float wun = wih[(1024 + col) * 258 + 256], wvn = wih[(1024 + col) * 258 + 257];
      const float gr = vR[j] + br + u0 * wur + u1 * wvr;
      const float gz = vZ[j] + bz + u0 * wuz + u1 * wvz;
      const float gxn = vXN[j] + bxn + u0 * wun + u1 * wvn;
      const float ghn = vHN[j] + bhn;
      const float rg = 1.0f / (1.0f + __expf(-gr));
      const float zg = 1.0f / (1.0f + __expf(-gz));
      float xn = gxn + rg * ghn;
      xn = fminf(fmaxf(xn, -15.0f), 15.0f);
      const float e = __expf(2.0f * xn);
      const float ng = (e - 1.0f) / (e + 1.0f);
      const float hp = (t > 0) ? (float)hb_in[row * 512 + col] : 0.0f;
      const float hnv = (1.0f - zg) * ng + zg * hp;
      hb_out[row * 512 + col] = __float2bfloat16(hnv);
    }
  }
}

// ---------------- pred, split-K-4: 512 blocks x 256 thr (4 waves) ----------------
__global__ __launch_bounds__(256) void pred_v2(
    const __hip_bfloat16* __restrict__ hb,
    const __hip_bfloat16* __restrict__ pwb,    // [256][512]
    const float* __restrict__ pb,
    float* __restrict__ out,
    __hip_bfloat16* __restrict__ spb,
    int slot) {
  __shared__ float accL[4][256];
  const int tid = threadIdx.x;
  const int w = tid >> 6, lane = tid & 63;
  const int l15 = lane & 15, hi = lane >> 4;
  const int pcg = blockIdx.x, band = blockIdx.y;
  const int row0 = band * 16, pc0 = pcg * 16;
  f32x4 acc = {0.f, 0.f, 0.f, 0.f};
  const __hip_bfloat16* A = hb + (row0 + l15) * 512 + w * 128 + hi * 8;
  const __hip_bfloat16* B = pwb + (pc0 + l15) * 512 + w * 128 + hi * 8;
#pragma unroll
  for (int kk = 0; kk < 4; ++kk)
    acc = __builtin_amdgcn_mfma_f32_16x16x32_bf16(*(const bf16x8*)(A + kk * 32),
                                                  *(const bf16x8*)(B + kk * 32),
                                                  acc, 0, 0, 0);
#pragma unroll
  for (int i = 0; i < 4; ++i) accL[w][(hi * 4 + i) * 16 + l15] = acc[i];
  __syncthreads();
  if (w == 0) {
    f32x4 p0 = *(const f32x4*)&accL[0][lane * 4];
    f32x4 p1 = *(const f32x4*)&accL[1][lane * 4];
    f32x4 p2 = *(const f32x4*)&accL[2][lane * 4];
    f32x4 p3 = *(const f32x4*)&accL[3][lane * 4];
    const int r = lane >> 2;
    const int row = row0 + r;
    float4 ov;
    float* po = &ov.x;
#pragma unroll
    for (int j = 0; j < 4; ++j) {
      const int c = (lane & 3) * 4 + j;
      const int col = pc0 + c;
      float v = p0[j] + p1[j] + p2[j] + p3[j] + pb[col];
      v = fmaxf(v, 0.0f);
      po[j] = v;
      spb[row * 256 + col] = __float2bfloat16(v);
    }
    *(float4*)(out + ((size_t)row * TT + slot) * 256 + pc0 + (lane & 3) * 4) = ov;
  }
}

extern "C" void kernel_launch(void* const* d_in, const int* in_sizes, int n_in,
                              void* d_out, int out_size, void* d_ws, size_t ws_size,
                              hipStream_t stream) {
  const float* x       = (const float*)d_in[0];
  const float* actions = (const float*)d_in[1];
  const float* cw      = (const float*)d_in[2];
  const float* gamma   = (const float*)d_in[3];
  const float* beta    = (const float*)d_in[4];
  const float* fcw     = (const float*)d_in[5];
  const float* fcb     = (const float*)d_in[6];
  const float* wih     = (const float*)d_in[7];
  const float* whh     = (const float*)d_in[8];
  const float* bih     = (const float*)d_in[9];
  const float* bhh     = (const float*)d_in[10];
  const float* pw      = (const float*)d_in[11];
  const float* pb      = (const float*)d_in[12];
  float* out = (float*)d_out;
  float* ws  = (float*)d_ws;

  float* bstats = ws + OFF_BSTATS;
  __hip_bfloat16* spb  = (__hip_bfloat16*)(ws + OFF_SPB);
  __hip_bfloat16* pwb  = (__hip_bfloat16*)(ws + OFF_PWB);
  __hip_bfloat16* wihb = (__hip_bfloat16*)(ws + OFF_WIHB);
  __hip_bfloat16* whhb = (__hip_bfloat16*)(ws + OFF_WHHB);
  __hip_bfloat16* hb0  = (__hip_bfloat16*)(ws + OFF_HB);
  __hip_bfloat16* hb1  = hb0 + 512 * 512;

  enc_stats_prep<<<dim3(512), dim3(256), 0, stream>>>(x, cw, bstats, wih, whh, pw,
                                                      wihb, whhb, pwb);
  enc_finish<<<dim3(512), dim3(256), 0, stream>>>(x, cw, bstats, gamma, beta, fcw, fcb,
                                                  spb, out);
  for (int t = 0; t < TM1; ++t) {
    __hip_bfloat16* hbi = (t & 1) ? hb1 : hb0;
    __hip_bfloat16* hbo = (t & 1) ? hb0 : hb1;
    gru_v2<<<dim3(16, 32), dim3(384), 0, stream>>>(spb, hbi, hbo, wihb, whhb,
                                                   wih, actions, bih, bhh, t);
    pred_v2<<<dim3(16, 32), dim3(256), 0, stream>>>(hbo, pwb, pb, out, spb, t + 1);
  }
}